// Round 1
// baseline (524.168 us; speedup 1.0000x reference)
//
#include <hip/hip_runtime.h>
#include <hip/hip_bf16.h>
#include <cstdint>
#include <cstddef>

#define EPS 1e-8f
#define H_T 2.0794415416798357f /* ln(8) */

typedef __attribute__((ext_vector_type(8))) short bf16x8;
typedef __attribute__((ext_vector_type(4))) float f32x4;

__device__ __forceinline__ unsigned short f2bf(float f) {
    union { float f; unsigned u; } v; v.f = f;
    unsigned r = v.u + 0x7fffu + ((v.u >> 16) & 1u);
    return (unsigned short)(r >> 16);
}

// ---------------- elementwise f32 -> bf16 ----------------
__global__ void conv_bf16(const float* __restrict__ in, unsigned short* __restrict__ out, int n) {
    int i = blockIdx.x * blockDim.x + threadIdx.x;
    if (i < n) out[i] = f2bf(in[i]);
}

// ---------------- transpose + convert: in(R x C) f32 -> out(C x R) bf16 ----------------
__global__ __launch_bounds__(256) void transpose_bf16(const float* __restrict__ in,
                                                      unsigned short* __restrict__ out,
                                                      int R, int C) {
    __shared__ float tile[32][33];
    int c0 = blockIdx.x * 32, r0 = blockIdx.y * 32;
    int tx = threadIdx.x & 31, ty = threadIdx.x >> 5; // ty in [0,8)
#pragma unroll
    for (int i = 0; i < 4; i++) {
        int r = ty + i * 8;
        tile[r][tx] = in[(size_t)(r0 + r) * C + c0 + tx];
    }
    __syncthreads();
#pragma unroll
    for (int i = 0; i < 4; i++) {
        int c = ty + i * 8;
        out[(size_t)(c0 + c) * R + r0 + tx] = f2bf(tile[tx][c]);
    }
}

// ---------------- GEMM1: C(MxN) = A(MxK) * BT(NxK)^T + bias, f32 out ----------------
// 64x64 tile, 256 threads, 2x2 waves, 16x16x32 bf16 MFMA, BK=32
__global__ __launch_bounds__(256) void gemm_bias(const unsigned short* __restrict__ A,
                                                 const unsigned short* __restrict__ BT,
                                                 const float* __restrict__ bias,
                                                 float* __restrict__ C,
                                                 int M, int N, int K) {
    __shared__ unsigned short lA[64 * 40];
    __shared__ unsigned short lB[64 * 40];
    int m0 = blockIdx.x * 64, n0 = blockIdx.y * 64;
    int tid = threadIdx.x;
    int lane = tid & 63, wave = tid >> 6;
    int wm = wave >> 1, wn = wave & 1;
    int r = lane & 15, q = lane >> 4;

    f32x4 acc[2][2];
#pragma unroll
    for (int i = 0; i < 2; i++)
#pragma unroll
        for (int j = 0; j < 2; j++) acc[i][j] = (f32x4){0.f, 0.f, 0.f, 0.f};

    int ldrow = tid >> 2, ldc = (tid & 3) * 8;

    for (int kk = 0; kk < K; kk += 32) {
        uint4 av = *(const uint4*)(A + (size_t)(m0 + ldrow) * K + kk + ldc);
        uint4 bv = *(const uint4*)(BT + (size_t)(n0 + ldrow) * K + kk + ldc);
        __syncthreads();
        *(uint4*)(&lA[ldrow * 40 + ldc]) = av;
        *(uint4*)(&lB[ldrow * 40 + ldc]) = bv;
        __syncthreads();

        bf16x8 a0 = *(const bf16x8*)(&lA[(wm * 32 + r) * 40 + q * 8]);
        bf16x8 a1 = *(const bf16x8*)(&lA[(wm * 32 + 16 + r) * 40 + q * 8]);
        bf16x8 b0 = *(const bf16x8*)(&lB[(wn * 32 + r) * 40 + q * 8]);
        bf16x8 b1 = *(const bf16x8*)(&lB[(wn * 32 + 16 + r) * 40 + q * 8]);
        acc[0][0] = __builtin_amdgcn_mfma_f32_16x16x32_bf16(a0, b0, acc[0][0], 0, 0, 0);
        acc[0][1] = __builtin_amdgcn_mfma_f32_16x16x32_bf16(a0, b1, acc[0][1], 0, 0, 0);
        acc[1][0] = __builtin_amdgcn_mfma_f32_16x16x32_bf16(a1, b0, acc[1][0], 0, 0, 0);
        acc[1][1] = __builtin_amdgcn_mfma_f32_16x16x32_bf16(a1, b1, acc[1][1], 0, 0, 0);
    }

#pragma unroll
    for (int i = 0; i < 2; i++)
#pragma unroll
        for (int j = 0; j < 2; j++)
#pragma unroll
            for (int reg = 0; reg < 4; reg++) {
                int row = m0 + wm * 32 + i * 16 + q * 4 + reg;
                int col = n0 + wn * 32 + j * 16 + r;
                C[(size_t)row * N + col] = acc[i][j][reg] + bias[col];
            }
}

// ---------------- RMSNorm: x(4096x512) f32 -> xn(4096x512) bf16 ----------------
__global__ __launch_bounds__(256) void rms_kernel(const float* __restrict__ x,
                                                  const float* __restrict__ norm_w,
                                                  unsigned short* __restrict__ xn) {
    int m = blockIdx.x;
    int tid = threadIdx.x;
    const float* row = x + (size_t)m * 512;
    float v0 = row[tid];
    float v1 = row[tid + 256];
    float ss = v0 * v0 + v1 * v1;
#pragma unroll
    for (int o = 32; o > 0; o >>= 1) ss += __shfl_down(ss, o);
    __shared__ float rs[4];
    __shared__ float scale_sh;
    int lane = tid & 63, wave = tid >> 6;
    if (lane == 0) rs[wave] = ss;
    __syncthreads();
    if (tid == 0) {
        float tot = rs[0] + rs[1] + rs[2] + rs[3];
        scale_sh = 1.0f / sqrtf(tot * (1.0f / 512.0f) + 1e-6f);
    }
    __syncthreads();
    float s = scale_sh;
    xn[(size_t)m * 512 + tid] = f2bf(v0 * s * norm_w[tid]);
    xn[(size_t)m * 512 + tid + 256] = f2bf(v1 * s * norm_w[tid + 256]);
}

// ---------------- GEMM2 + softmax/cumsum/loss, fused ----------------
// M=4096, N=8192, K=512. 64x64 tile => 8 b's x 64 k's per block.
__global__ __launch_bounds__(256) void gemm_loss(const unsigned short* __restrict__ A,
                                                 const unsigned short* __restrict__ BT,
                                                 const int* __restrict__ is_event,
                                                 const int* __restrict__ is_cens,
                                                 const float* __restrict__ ratio,
                                                 float* __restrict__ accum) {
    const int K = 512, NK = 8192;
    __shared__ unsigned short lA[64 * 40];
    __shared__ unsigned short lB[64 * 40];
    __shared__ float lg[64 * 65];
    __shared__ float rsum[4];
    __shared__ int rcnt[4];

    int m0 = blockIdx.x * 64, n0 = blockIdx.y * 64;
    int tid = threadIdx.x;
    int lane = tid & 63, wave = tid >> 6;
    int wm = wave >> 1, wn = wave & 1;
    int r = lane & 15, q = lane >> 4;

    f32x4 acc[2][2];
#pragma unroll
    for (int i = 0; i < 2; i++)
#pragma unroll
        for (int j = 0; j < 2; j++) acc[i][j] = (f32x4){0.f, 0.f, 0.f, 0.f};

    int ldrow = tid >> 2, ldc = (tid & 3) * 8;

    for (int kk = 0; kk < K; kk += 32) {
        uint4 av = *(const uint4*)(A + (size_t)(m0 + ldrow) * K + kk + ldc);
        uint4 bv = *(const uint4*)(BT + (size_t)(n0 + ldrow) * K + kk + ldc);
        __syncthreads();
        *(uint4*)(&lA[ldrow * 40 + ldc]) = av;
        *(uint4*)(&lB[ldrow * 40 + ldc]) = bv;
        __syncthreads();

        bf16x8 a0 = *(const bf16x8*)(&lA[(wm * 32 + r) * 40 + q * 8]);
        bf16x8 a1 = *(const bf16x8*)(&lA[(wm * 32 + 16 + r) * 40 + q * 8]);
        bf16x8 b0 = *(const bf16x8*)(&lB[(wn * 32 + r) * 40 + q * 8]);
        bf16x8 b1 = *(const bf16x8*)(&lB[(wn * 32 + 16 + r) * 40 + q * 8]);
        acc[0][0] = __builtin_amdgcn_mfma_f32_16x16x32_bf16(a0, b0, acc[0][0], 0, 0, 0);
        acc[0][1] = __builtin_amdgcn_mfma_f32_16x16x32_bf16(a0, b1, acc[0][1], 0, 0, 0);
        acc[1][0] = __builtin_amdgcn_mfma_f32_16x16x32_bf16(a1, b0, acc[1][0], 0, 0, 0);
        acc[1][1] = __builtin_amdgcn_mfma_f32_16x16x32_bf16(a1, b1, acc[1][1], 0, 0, 0);
    }

    // stage logits tile to LDS (lg is distinct memory; sync only after writes)
#pragma unroll
    for (int i = 0; i < 2; i++)
#pragma unroll
        for (int j = 0; j < 2; j++)
#pragma unroll
            for (int reg = 0; reg < 4; reg++) {
                int row = wm * 32 + i * 16 + q * 4 + reg;
                int col = wn * 32 + j * 16 + r;
                lg[row * 65 + col] = acc[i][j][reg];
            }
    __syncthreads();

    float lsum = 0.0f;
    int lcnt = 0;
#pragma unroll
    for (int p = 0; p < 2; p++) {
        int idx = tid + p * 256;          // 512 (b,k) pairs per block
        int bl = idx >> 6, kl = idx & 63; // bl in [0,8), kl in [0,64)
        int b = (m0 >> 3) + bl;
        int k = n0 + kl;

        float L[8];
#pragma unroll
        for (int t = 0; t < 8; t++) L[t] = lg[(bl * 8 + t) * 65 + kl];
        float mx = L[0];
#pragma unroll
        for (int t = 1; t < 8; t++) mx = fmaxf(mx, L[t]);
        float e[8], s = 0.0f;
#pragma unroll
        for (int t = 0; t < 8; t++) { e[t] = __expf(L[t] - mx); s += e[t]; }
        float inv = 1.0f / s;

        int cen = is_cens[(size_t)b * NK + k];
        size_t base = ((size_t)b * 8) * NK + k;
        float cum = 0.0f;
#pragma unroll
        for (int t = 0; t < 8; t++) {
            float pt = e[t] * inv;
            float integ = 1.0f - cum;
            cum += pt;
            int ev = is_event[base + (size_t)t * NK];
            if (ev) {
                lcnt++;
                float ps = fminf(fmaxf(pt, EPS), 1.0f - EPS);
                float sel;
                if (cen) {
                    float is_ = fminf(fmaxf(integ, EPS), 1.0f - EPS);
                    float v = is_ - ratio[base + (size_t)t * NK] * ps;
                    sel = fminf(fmaxf(v, EPS), 1.0f - EPS);
                } else {
                    sel = ps;
                }
                lsum += logf(sel);
            }
        }
    }

    // block reduction
#pragma unroll
    for (int o = 32; o > 0; o >>= 1) {
        lsum += __shfl_down(lsum, o);
        lcnt += __shfl_down(lcnt, o);
    }
    if (lane == 0) { rsum[wave] = lsum; rcnt[wave] = lcnt; }
    __syncthreads();
    if (tid == 0) {
        float bs = rsum[0] + rsum[1] + rsum[2] + rsum[3];
        int bc = rcnt[0] + rcnt[1] + rcnt[2] + rcnt[3];
        atomicAdd(&accum[0], bs);
        atomicAdd((unsigned*)&accum[1], (unsigned)bc);
    }
}

__global__ void finalize_kernel(const float* __restrict__ accum, float* __restrict__ out) {
    float s = accum[0];
    unsigned c = *(const unsigned*)&accum[1];
    out[0] = -s / ((float)c * H_T);
}

extern "C" void kernel_launch(void* const* d_in, const int* in_sizes, int n_in,
                              void* d_out, int out_size, void* d_ws, size_t ws_size,
                              hipStream_t stream) {
    const float* features = (const float*)d_in[0]; // 512x768
    const float* W1       = (const float*)d_in[1]; // 768x4096
    const float* b1       = (const float*)d_in[2]; // 4096
    const float* norm_w   = (const float*)d_in[3]; // 512
    const float* W2       = (const float*)d_in[4]; // 512x8192
    /* b2 (d_in[5]) is softmax(axis=1)-invariant: skipped */
    const int* is_event   = (const int*)d_in[6];   // 512x8x8192 (bool as i32)
    const int* is_cens    = (const int*)d_in[7];   // 512x8192  (bool as i32)
    const float* ratio    = (const float*)d_in[8]; // 512x8x8192
    float* out = (float*)d_out;

    char* ws = (char*)d_ws;
    size_t off = 0;
    auto alloc = [&](size_t bytes) { void* p = ws + off; off = (off + bytes + 255) & ~(size_t)255; return p; };
    unsigned short* W1T    = (unsigned short*)alloc((size_t)4096 * 768 * 2);
    unsigned short* W2T    = (unsigned short*)alloc((size_t)8192 * 512 * 2);
    unsigned short* featbf = (unsigned short*)alloc((size_t)512 * 768 * 2);
    float*          xbuf   = (float*)alloc((size_t)512 * 4096 * 4);
    unsigned short* xn     = (unsigned short*)alloc((size_t)4096 * 512 * 2);
    float*          accum  = (float*)alloc(16);

    hipMemsetAsync(accum, 0, 16, stream);

    conv_bf16<<<(512 * 768) / 256, 256, 0, stream>>>(features, featbf, 512 * 768);
    transpose_bf16<<<dim3(4096 / 32, 768 / 32), 256, 0, stream>>>(W1, W1T, 768, 4096);
    transpose_bf16<<<dim3(8192 / 32, 512 / 32), 256, 0, stream>>>(W2, W2T, 512, 8192);

    gemm_bias<<<dim3(512 / 64, 4096 / 64), 256, 0, stream>>>(featbf, W1T, b1, xbuf, 512, 4096, 768);
    rms_kernel<<<4096, 256, 0, stream>>>(xbuf, norm_w, xn);
    gemm_loss<<<dim3(4096 / 64, 8192 / 64), 256, 0, stream>>>(xn, W2T, is_event, is_cens, ratio, accum);
    finalize_kernel<<<1, 1, 0, stream>>>(accum, out);
}